// Round 21
// baseline (156.563 us; speedup 1.0000x reference)
//
#include <hip/hip_runtime.h>

typedef unsigned short ushort_t;
typedef unsigned long long u64_t;
typedef __attribute__((ext_vector_type(8))) unsigned char v8uc;
typedef __attribute__((ext_vector_type(8))) unsigned short v8us;
typedef __attribute__((ext_vector_type(8))) short v8bf;
typedef __attribute__((ext_vector_type(4))) float v4f;

#define BROWS 4096
#define DIMK 256
#define QN 32768
#define EXPSCALE 14.426950408889634f   // 10 * log2(e)

#if defined(__has_builtin)
#if __has_builtin(__builtin_amdgcn_cvt_pk_fp8_f32)
#define HAS_HW_FP8 1
#endif
#endif

__device__ __forceinline__ ushort_t f2bf(float f) {
    unsigned u = __float_as_uint(f);
    return (ushort_t)((u + 0x7FFFu + ((u >> 16) & 1u)) >> 16);   // RNE
}
__device__ __forceinline__ float bf2f(ushort_t u) {
    return __uint_as_float(((unsigned)u) << 16);
}
// f32 -> OCP e4m3fn, RNE (fallback path)
__device__ __forceinline__ unsigned char f2e4m3(float f) {
    unsigned u = __float_as_uint(f);
    unsigned s = (u >> 24) & 0x80u;
    int exp = (int)((u >> 23) & 0xFFu) - 127;
    unsigned man = u & 0x7FFFFFu;
    if (exp >= -6) {
        unsigned m = man >> 20;
        unsigned rest = man & 0xFFFFFu;
        if (rest > 0x80000u || (rest == 0x80000u && (m & 1u))) m++;
        if (m == 8u) { m = 0u; exp++; }
        if (exp > 8) return (unsigned char)(s | 0x7Eu);
        return (unsigned char)(s | ((unsigned)(exp + 7) << 3) | m);
    }
    if (exp < -10) return (unsigned char)s;
    unsigned full = man | 0x800000u;
    int shift = 20 + (-6 - exp);
    unsigned m = full >> shift;
    unsigned rest = full & ((1u << shift) - 1u);
    unsigned half = 1u << (shift - 1);
    if (rest > half || (rest == half && (m & 1u))) m++;
    if (m == 8u) return (unsigned char)(s | (1u << 3));
    return (unsigned char)(s | m);
}
// 8 floats -> 8 fp8 bytes (HW packed cvt when available)
__device__ __forceinline__ u64_t cvt8_fp8(const float* v) {
#ifdef HAS_HW_FP8
    int lo = 0, hi = 0;
    lo = __builtin_amdgcn_cvt_pk_fp8_f32(v[0], v[1], lo, false);
    lo = __builtin_amdgcn_cvt_pk_fp8_f32(v[2], v[3], lo, true);
    hi = __builtin_amdgcn_cvt_pk_fp8_f32(v[4], v[5], hi, false);
    hi = __builtin_amdgcn_cvt_pk_fp8_f32(v[6], v[7], hi, true);
    return ((u64_t)(unsigned)hi << 32) | (u64_t)(unsigned)lo;
#else
    u64_t r = 0;
#pragma unroll
    for (int q = 0; q < 8; ++q) r |= (u64_t)f2e4m3(v[q]) << (8 * q);
    return r;
#endif
}
__device__ __forceinline__ u64_t shfl_xor_u64(u64_t v, int off) {
    unsigned lo = (unsigned)(v & 0xFFFFFFFFull);
    unsigned hi = (unsigned)(v >> 32);
    lo = (unsigned)__shfl_xor((int)lo, off, 64);
    hi = (unsigned)__shfl_xor((int)hi, off, 64);
    return ((u64_t)hi << 32) | (u64_t)lo;
}
#define GLOAD(g, l_) __builtin_amdgcn_global_load_lds(                         \
    (const __attribute__((address_space(1))) void*)(g),                        \
    (__attribute__((address_space(3))) void*)(l_), 16, 0, 0)

// ==================== conv_all: queue->fp8, packed zero, F->bf16, W^T ====================
__global__ __launch_bounds__(256) void conv_all(const float* __restrict__ queue,
                                                const float* __restrict__ F1,
                                                const float* __restrict__ F2,
                                                const float* __restrict__ W1,
                                                const float* __restrict__ W2,
                                                unsigned char* __restrict__ qf8,
                                                ushort_t* __restrict__ Fb,
                                                ushort_t* __restrict__ WTb,
                                                u64_t* __restrict__ packed) {
    const int bid = blockIdx.x, j = threadIdx.x;
    if (bid < 4096) {
        if (bid < 32) packed[(bid << 8) + j] = 0ull;
        const size_t i = ((size_t)bid * 256 + j) * 8;
        float v[8];
        float4 x = *(const float4*)&queue[i];
        float4 y = *(const float4*)&queue[i + 4];
        v[0] = x.x; v[1] = x.y; v[2] = x.z; v[3] = x.w;
        v[4] = y.x; v[5] = y.y; v[6] = y.z; v[7] = y.w;
        const u64_t q = cvt8_fp8(v);
        const int row = (int)(i >> 8);
        const int col = (int)(i & 255);
        *(u64_t*)&qf8[((size_t)row << 8) + (col ^ ((((unsigned)row >> 3) & 1u) << 3))] = q;
        return;
    }
    if (bid < 5120) {
        const int idx = bid - 4096;                // 0..1023
        const int half = idx >> 9;
        const float* F = half ? F2 : F1;
        const size_t off = ((size_t)(idx & 511) * 256 + j) * 8;
        float4 x = *(const float4*)&F[off];
        float4 y = *(const float4*)&F[off + 4];
        v8us o;
        o[0] = f2bf(x.x); o[1] = f2bf(x.y); o[2] = f2bf(x.z); o[3] = f2bf(x.w);
        o[4] = f2bf(y.x); o[5] = f2bf(y.y); o[6] = f2bf(y.z); o[7] = f2bf(y.w);
        *(v8us*)&Fb[(size_t)half * BROWS * DIMK + off] = o;
        return;
    }
    const int s = bid - 5120;
    const int mtx = s >> 4;
    const int n0 = (s & 15) << 4;
    const float* Wsrc = mtx ? W2 : W1;
    float tmp[16];
#pragma unroll
    for (int r = 0; r < 16; ++r) tmp[r] = Wsrc[(size_t)j * 256 + n0 + r];
#pragma unroll
    for (int r = 0; r < 16; ++r)
        WTb[(size_t)mtx * 65536 + (size_t)(n0 + r) * 256 + j] = f2bf(tmp[r]);
}

// ==================== proj_mfma: 2-layer MLP + L2 norm -> fp8 (R20-proven) ====================
__global__ __launch_bounds__(256) void proj_mfma(const ushort_t* __restrict__ Fb,
                                                 const ushort_t* __restrict__ WTb,
                                                 const float* __restrict__ b1,
                                                 const float* __restrict__ b2,
                                                 unsigned char* __restrict__ pf8) {
    __shared__ __align__(16) ushort_t Fa[32 * 256];
    __shared__ __align__(16) ushort_t hb[32 * 256];
    __shared__ __align__(16) ushort_t Bw[128 * 64];
    __shared__ float sums[32][2];
    const int tid = threadIdx.x;
    const int w = tid >> 6, l = tid & 63;
    const int wr = w >> 1, wc = w & 1;
    const int lo = l >> 4;

    const int half = blockIdx.x >> 7;
    const int rb = blockIdx.x & 127;
    const int grow0 = (half << 12) + (rb << 5);

    if (tid < 64) sums[tid >> 1][tid & 1] = 0.f;

#pragma unroll
    for (int j = 0; j < 4; ++j) {
        const int slot = (j << 8) + tid;
        const int row = slot >> 5, s = slot & 31;
        const int oct = (s & ~7) | ((s & 7) ^ (row & 7));
        GLOAD(&Fb[(size_t)(grow0 + row) * 256 + (oct << 3)],
              (ushort_t*)Fa + (((j << 8) + (w << 6)) << 3));
    }

#pragma unroll
    for (int layer = 0; layer < 2; ++layer) {
        const ushort_t* WT = WTb + (size_t)layer * 65536;
        const ushort_t* Areg = layer ? hb : Fa;
        const float* bias = layer ? b2 : b1;
#pragma unroll
        for (int cp = 0; cp < 2; ++cp) {
            v4f acc[4];
#pragma unroll
            for (int n = 0; n < 4; ++n) acc[n] = (v4f){0.f, 0.f, 0.f, 0.f};
            for (int ph = 0; ph < 4; ++ph) {
#pragma unroll
                for (int j = 0; j < 4; ++j) {
                    const int slot = (j << 8) + tid;
                    const int row = slot >> 3, m = slot & 7;
                    const int ms = m ^ (row & 7);
                    GLOAD(&WT[(size_t)((cp << 7) + row) * 256 + (ph << 6) + (ms << 3)],
                          (ushort_t*)Bw + (((j << 8) + (w << 6)) << 3));
                }
                __syncthreads();
#pragma unroll
                for (int kk = 0; kk < 2; ++kk) {
                    const int k32 = (ph << 1) + kk;
                    const int arow = (wr << 4) + (l & 15);
                    const int aphys = ((k32 >> 1) << 3) |
                                      ((((k32 & 1) << 2) + lo) ^ (arow & 7));
                    v8bf av = *(const v8bf*)&Areg[(arow << 8) + (aphys << 3)];
#pragma unroll
                    for (int nj = 0; nj < 4; ++nj) {
                        const int brow = (wc << 6) + (nj << 4) + (l & 15);
                        const int bphys = ((kk << 2) + lo) ^ (brow & 7);
                        v8bf bv = *(const v8bf*)&Bw[(brow << 6) + (bphys << 3)];
                        acc[nj] = __builtin_amdgcn_mfma_f32_16x16x32_bf16(
                            av, bv, acc[nj], 0, 0, 0);
                    }
                }
                __syncthreads();
            }
#pragma unroll
            for (int nj = 0; nj < 4; ++nj) {
                const int col = (cp << 7) + (wc << 6) + (nj << 4) + (l & 15);
                const float bb = bias[col];
                const int o = col >> 3, q = col & 7;
                float sq[4];
#pragma unroll
                for (int r = 0; r < 4; ++r) {
                    const int row = (wr << 4) + (lo << 2) + r;
                    float v = acc[nj][r] + bb;
                    if (layer == 0) v = v > 0.f ? v : 0.f;
                    const int po = (o & ~7) | ((o & 7) ^ (row & 7));
                    if (layer == 0) hb[(row << 8) + (po << 3) + q] = f2bf(v);
                    else            Fa[(row << 8) + (po << 3) + q] = f2bf(v);
                    sq[r] = v * v;
                }
                if (layer == 1) {
#pragma unroll
                    for (int r = 0; r < 4; ++r) {
                        float s = sq[r];
                        s += __shfl_xor(s, 1); s += __shfl_xor(s, 2);
                        s += __shfl_xor(s, 4); s += __shfl_xor(s, 8);
                        sq[r] = s;
                    }
#pragma unroll
                    for (int r = 0; r < 4; ++r)
                        if ((l & 15) == 0)
                            sums[(wr << 4) + (lo << 2) + r][wc] += sq[r];
                }
            }
        }
        __syncthreads();
    }

    const int row = tid >> 3;
    const int cb = (tid & 7) << 5;
    const float tot = sums[row][0] + sums[row][1];
    const float inv = 1.f / fmaxf(sqrtf(tot), 1e-12f);
    const int prow = grow0 + row;
    const unsigned par = ((unsigned)prow >> 3) & 1u;
#pragma unroll
    for (int cc = 0; cc < 4; ++cc) {
        const int c0 = cb + (cc << 3);
        const int o = c0 >> 3;
        const int po = (o & ~7) | ((o & 7) ^ (row & 7));
        float v[8];
#pragma unroll
        for (int q = 0; q < 8; ++q)
            v[q] = bf2f(Fa[(row << 8) + (po << 3) + q]) * inv;
        *(u64_t*)&pf8[((size_t)prow << 8) + ((unsigned)c0 ^ (par << 3))] = cvt8_fp8(v);
    }
}

// ==================== shared fp8 GEMM shell (R17-proven) + T5 setprio ====================
__device__ __forceinline__ void stage_b8(const unsigned char* __restrict__ B, int col0,
                                         int kbyte, unsigned char* dst, int tid, int w) {
#pragma unroll
    for (int j = 0; j < 4; ++j) {
        const int slot = (j << 8) + tid;
        const int row = slot >> 3, m = slot & 7;
        const int ms = m ^ (row & 7);
        GLOAD(&B[(size_t)(col0 + row) * DIMK + kbyte + (ms << 4)],
              dst + (((j << 8) + (w << 6)) << 4));
    }
}
__device__ __forceinline__ void stage_a8(const unsigned char* __restrict__ A, int arow0,
                                         unsigned char* Alds, int tid, int w) {
#pragma unroll
    for (int j = 0; j < 8; ++j) {
        const int slot = (j << 8) + tid;
        const int row = slot >> 4, m = slot & 15;
        const int ms = m ^ (row & 15);
        GLOAD(&A[(size_t)(arow0 + row) * DIMK + (ms << 4)],
              Alds + (((j << 8) + (w << 6)) << 4));
    }
}

__global__ __launch_bounds__(256, 2) void nn_argmax8(const unsigned char* __restrict__ Pf8,
                                                     const unsigned char* __restrict__ Qf8,
                                                     u64_t* __restrict__ packed) {
    __shared__ __align__(16) unsigned char Alds[128 * 256];
    __shared__ __align__(16) unsigned char Bs[2][128 * 128];
    const int tid = threadIdx.x;
    const int w = tid >> 6, l = tid & 63;
    const int wr = w >> 1, wc = w & 1;

    const int bid = blockIdx.x;
    const int xcd = bid & 7, i = bid >> 3;
    const int half = xcd & 1;
    const int pairgrp = xcd >> 1;
    const int arow0 = (i & 31) << 7;
    const int colbase = (pairgrp << 13) + ((i >> 5) << 12);
    const unsigned char* A = Pf8 + (size_t)half * BROWS * DIMK;
    const unsigned char* B = Qf8;
    u64_t* pk_out = packed + (size_t)half * BROWS;

    stage_a8(A, arow0, Alds, tid, w);
    stage_b8(B, colbase, 0, &Bs[0][0], tid, w);
    __syncthreads();

    unsigned best[4][4];
#pragma unroll
    for (int a = 0; a < 4; ++a)
#pragma unroll
        for (int r = 0; r < 4; ++r) best[a][r] = 0u;

    for (int t = 0; t < 32; ++t) {
        v4f acc[4][4];
#pragma unroll
        for (int a = 0; a < 4; ++a)
#pragma unroll
            for (int b = 0; b < 4; ++b) acc[a][b] = (v4f){2.f, 2.f, 2.f, 2.f};

#pragma unroll
        for (int kh = 0; kh < 2; ++kh) {
            const int p = (t << 1) + kh;
            if (p + 1 < 64) {
                const int tn = (p + 1) >> 1, kn = (p + 1) & 1;
                stage_b8(B, colbase + (tn << 7), kn << 7, &Bs[(p + 1) & 1][0], tid, w);
            }
            const unsigned char* bufr = &Bs[p & 1][0];
#pragma unroll
            for (int c = 0; c < 4; ++c) {
                long av[4], bv[4];
#pragma unroll
                for (int mi = 0; mi < 4; ++mi) {
                    const int row = (wr << 6) + (mi << 4) + (l & 15);
                    const int o = (kh << 4) + (c << 2) + (l >> 4);
                    const int phys = (((o >> 1) ^ (row & 15)) << 4) +
                                     (((o ^ (row >> 3)) & 1) << 3);
                    av[mi] = *(const long*)&Alds[(row << 8) + phys];
                }
#pragma unroll
                for (int nj = 0; nj < 4; ++nj) {
                    const int row = (wc << 6) + (nj << 4) + (l & 15);
                    const int o = (c << 2) + (l >> 4);
                    const int phys = (((o >> 1) ^ (row & 7)) << 4) +
                                     (((o ^ (row >> 3)) & 1) << 3);
                    bv[nj] = *(const long*)&bufr[(row << 7) + phys];
                }
                __builtin_amdgcn_s_setprio(1);   // T5: favor MFMA-issuing wave
#pragma unroll
                for (int mi = 0; mi < 4; ++mi)
#pragma unroll
                    for (int nj = 0; nj < 4; ++nj)
                        acc[mi][nj] = __builtin_amdgcn_mfma_f32_16x16x32_fp8_fp8(
                            av[mi], bv[nj], acc[mi][nj], 0, 0, 0);
                __builtin_amdgcn_s_setprio(0);
            }
            __syncthreads();
        }
#pragma unroll
        for (int mi = 0; mi < 4; ++mi)
#pragma unroll
            for (int r = 0; r < 4; ++r) {
                unsigned m = (__float_as_uint(acc[mi][0][r]) & 0xFFFFFF80u) |
                             ((unsigned)t << 2);
#pragma unroll
                for (int nj = 1; nj < 4; ++nj) {
                    unsigned c = (__float_as_uint(acc[mi][nj][r]) & 0xFFFFFF80u) |
                                 ((unsigned)t << 2) | (unsigned)nj;
                    m = c > m ? c : m;
                }
                if (m > best[mi][r]) best[mi][r] = m;
            }
    }

#pragma unroll
    for (int mi = 0; mi < 4; ++mi)
#pragma unroll
        for (int r = 0; r < 4; ++r) {
            const unsigned wb = best[mi][r];
            const unsigned col = (unsigned)(colbase + (int)(((wb >> 2) & 31u) << 7) +
                                            (wc << 6) + (int)((wb & 3u) << 4)) + (l & 15);
            u64_t pk = ((u64_t)wb << 32) | (u64_t)(0xFFFFFFFFu - col);
#pragma unroll
            for (int off = 1; off < 16; off <<= 1) {
                u64_t o = shfl_xor_u64(pk, off);
                if (o > pk) pk = o;
            }
            if ((l & 15) == 0)
                atomicMax(&pk_out[arow0 + (wr << 6) + (mi << 4) + ((l >> 4) << 2) + r], pk);
        }
}

__global__ __launch_bounds__(256) void gather8(const u64_t* __restrict__ packed,
                                               const unsigned char* __restrict__ qf8,
                                               unsigned char* __restrict__ nn8,
                                               float* __restrict__ out) {
    if (blockIdx.x == 0 && threadIdx.x == 0) out[0] = 0.f;
    const int r8 = threadIdx.x >> 5;
    const int c = threadIdx.x & 31;
    for (int base = blockIdx.x * 8; base < 2 * BROWS; base += (int)gridDim.x * 8) {
        const int i = base + r8;
        const unsigned idx = 0xFFFFFFFFu - (unsigned)(packed[i] & 0xFFFFFFFFull);
        const unsigned sp = (idx >> 3) & 1u;
        const unsigned dp = (((unsigned)i) >> 3) & 1u;
        *(u64_t*)&nn8[((size_t)i << 8) + ((unsigned)(c << 3) ^ (dp << 3))] =
            *(const u64_t*)&qf8[((size_t)idx << 8) + ((unsigned)(c << 3) ^ (sp << 3))];
    }
}

__global__ __launch_bounds__(256, 2) void lse_gemm8(const unsigned char* __restrict__ nn8,
                                                    const unsigned char* __restrict__ pf8,
                                                    float* __restrict__ srp,
                                                    float* __restrict__ scp,
                                                    float* __restrict__ diag) {
    __shared__ __align__(16) unsigned char Alds[128 * 256];
    __shared__ __align__(16) unsigned char Bs[2][128 * 128];
    const int tid = threadIdx.x;
    const int w = tid >> 6, l = tid & 63;
    const int wr = w >> 1, wc = w & 1;

    const int z = blockIdx.x >> 8;
    const int i = blockIdx.x & 255;
    const int rowblk = i & 31;
    const int colstrip = i >> 5;
    const int arow0 = rowblk << 7;
    const int colbase = colstrip << 9;
    const unsigned char* A = nn8 + (size_t)z * BROWS * DIMK;
    const unsigned char* B = pf8 + (size_t)(1 - z) * BROWS * DIMK;
    float* dg = diag + (size_t)z * BROWS;

    stage_a8(A, arow0, Alds, tid, w);
    stage_b8(B, colbase, 0, &Bs[0][0], tid, w);
    __syncthreads();

    float rsum[4][4];
#pragma unroll
    for (int a = 0; a < 4; ++a)
#pragma unroll
        for (int r = 0; r < 4; ++r) rsum[a][r] = 0.f;

    for (int t = 0; t < 4; ++t) {
        v4f acc[4][4];
#pragma unroll
        for (int a = 0; a < 4; ++a)
#pragma unroll
            for (int b = 0; b < 4; ++b) acc[a][b] = (v4f){0.f, 0.f, 0.f, 0.f};

#pragma unroll
        for (int kh = 0; kh < 2; ++kh) {
            const int p = (t << 1) + kh;
            if (p + 1 < 8) {
                const int tn = (p + 1) >> 1, kn = (p + 1) & 1;
                stage_b8(B, colbase + (tn << 7), kn << 7, &Bs[(p + 1) & 1][0], tid, w);
            }
            const unsigned char* bufr = &Bs[p & 1][0];
#pragma unroll
            for (int c = 0; c < 4; ++c) {
                long av[4], bv[4];
#pragma unroll
                for (int mi = 0; mi < 4; ++mi) {
                    const int row = (wr << 6) + (mi << 4) + (l & 15);
                    const int o = (kh << 4) + (c << 2) + (l >> 4);
                    const int phys = (((o >> 1) ^ (row & 15)) << 4) +
                                     (((o ^ (row >> 3)) & 1) << 3);
                    av[mi] = *(const long*)&Alds[(row << 8) + phys];
                }
#pragma unroll
                for (int nj = 0; nj < 4; ++nj) {
                    const int row = (wc << 6) + (nj << 4) + (l & 15);
                    const int o = (c << 2) + (l >> 4);
                    const int phys = (((o >> 1) ^ (row & 7)) << 4) +
                                     (((o ^ (row >> 3)) & 1) << 3);
                    bv[nj] = *(const long*)&bufr[(row << 7) + phys];
                }
                __builtin_amdgcn_s_setprio(1);
#pragma unroll
                for (int mi = 0; mi < 4; ++mi)
#pragma unroll
                    for (int nj = 0; nj < 4; ++nj)
                        acc[mi][nj] = __builtin_amdgcn_mfma_f32_16x16x32_fp8_fp8(
                            av[mi], bv[nj], acc[mi][nj], 0, 0, 0);
                __builtin_amdgcn_s_setprio(0);
            }
            __syncthreads();
        }

        const int cb = colbase + (t << 7);
#pragma unroll
        for (int mi = 0; mi < 4; ++mi)
#pragma unroll
            for (int nj = 0; nj < 4; ++nj) {
                const int gr16 = arow0 + (wr << 6) + (mi << 4);
                const int gc16 = cb + (wc << 6) + (nj << 4);
                if (gr16 == gc16) {
#pragma unroll
                    for (int r = 0; r < 4; ++r) {
                        const int rr = ((l >> 4) << 2) + r;
                        if ((l & 15) == rr) dg[gr16 + rr] = acc[mi][nj][r] * 10.0f;
                    }
                }
            }
#pragma unroll
        for (int mi = 0; mi < 4; ++mi)
#pragma unroll
            for (int nj = 0; nj < 4; ++nj) {
                v4f tv = acc[mi][nj];
                tv[0] = exp2f(tv[0] * EXPSCALE);
                tv[1] = exp2f(tv[1] * EXPSCALE);
                tv[2] = exp2f(tv[2] * EXPSCALE);
                tv[3] = exp2f(tv[3] * EXPSCALE);
                acc[mi][nj] = tv;
            }
#pragma unroll
        for (int mi = 0; mi < 4; ++mi)
#pragma unroll
            for (int r = 0; r < 4; ++r) {
                float s = 0.f;
#pragma unroll
                for (int nj = 0; nj < 4; ++nj) s += acc[mi][nj][r];
                rsum[mi][r] += s;
            }
#pragma unroll
        for (int nj = 0; nj < 4; ++nj) {
            float s = 0.f;
#pragma unroll
            for (int mi = 0; mi < 4; ++mi)
#pragma unroll
                for (int r = 0; r < 4; ++r) s += acc[mi][nj][r];
            s += __shfl_xor(s, 16); s += __shfl_xor(s, 32);
            if (l < 16)
                scp[((size_t)(z << 6) + (rowblk << 1) + wr) * BROWS +
                    cb + (wc << 6) + (nj << 4) + l] = s;
        }
    }

#pragma unroll
    for (int mi = 0; mi < 4; ++mi)
#pragma unroll
        for (int r = 0; r < 4; ++r) {
            float s = rsum[mi][r];
            s += __shfl_xor(s, 1); s += __shfl_xor(s, 2);
            s += __shfl_xor(s, 4); s += __shfl_xor(s, 8);
            if ((l & 15) == 0)
                srp[((size_t)(z << 4) + (colstrip << 1) + wc) * BROWS +
                    arow0 + (wr << 6) + (mi << 4) + ((l >> 4) << 2) + r] = s;
        }
}

__global__ __launch_bounds__(256) void reduce_final(const float* __restrict__ srp,
                                                    const float* __restrict__ scp,
                                                    const float* __restrict__ diag,
                                                    float* __restrict__ out) {
    __shared__ float red[256];
    const int tid = threadIdx.x;
    const int idx = blockIdx.x * 256 + tid;
    const int z = idx >> 12, row = idx & 4095;
    float a = 0.f, b = 0.f;
#pragma unroll 4
    for (int s = 0; s < 16; ++s) a += srp[((size_t)(z << 4) + s) * BROWS + row];
#pragma unroll 4
    for (int s = 0; s < 64; ++s) b += scp[((size_t)(z << 6) + s) * BROWS + row];
    red[tid] = 2.f * diag[(size_t)z * BROWS + row] - logf(a) - logf(b);
    __syncthreads();
    for (int s = 128; s > 0; s >>= 1) {
        if (tid < s) red[tid] += red[tid + s];
        __syncthreads();
    }
    if (tid == 0) atomicAdd(out, -red[0] / (4.0f * (float)BROWS));
}

extern "C" void kernel_launch(void* const* d_in, const int* in_sizes, int n_in,
                              void* d_out, int out_size, void* d_ws, size_t ws_size,
                              hipStream_t stream) {
    const float* f1 = (const float*)d_in[0];
    const float* f2 = (const float*)d_in[1];
    const float* W1 = (const float*)d_in[2];
    const float* b1 = (const float*)d_in[3];
    const float* W2 = (const float*)d_in[4];
    const float* b2 = (const float*)d_in[5];
    const float* queue = (const float*)d_in[6];
    float* out = (float*)d_out;

    char* ws = (char*)d_ws;
    unsigned char* qf8 = (unsigned char*)ws;                    // 8 MB
    unsigned char* pf8 = (unsigned char*)(ws + (8ull << 20));   // 2 MB
    unsigned char* nn8 = (unsigned char*)(ws + (10ull << 20));  // 2 MB
    u64_t* packed = (u64_t*)(ws + (12ull << 20));               // 64 KB
    float* diag   = (float*)(ws + (12ull << 20) + (64ull << 10));   // 32 KB
    float* srp    = (float*)(ws + (12ull << 20) + (96ull << 10));   // 512 KB
    float* scp    = (float*)(ws + (12ull << 20) + (608ull << 10));  // 2 MB
    ushort_t* Fb  = (ushort_t*)(ws + (16ull << 20));            // 4 MB
    ushort_t* WTb = (ushort_t*)(ws + (20ull << 20));            // 256 KB

    conv_all<<<5152, 256, 0, stream>>>(queue, f1, f2, W1, W2, qf8, Fb, WTb, packed);
    proj_mfma<<<256, 256, 0, stream>>>(Fb, WTb, b1, b2, pf8);
    nn_argmax8<<<512, 256, 0, stream>>>(pf8, qf8, packed);
    gather8<<<256, 256, 0, stream>>>(packed, qf8, nn8, out);
    lse_gemm8<<<512, 256, 0, stream>>>(nn8, pf8, srp, scp, diag);
    reduce_final<<<32, 256, 0, stream>>>(srp, scp, diag, out);
}